// Round 5
// baseline (306.892 us; speedup 1.0000x reference)
//
#include <hip/hip_runtime.h>

#define NB 32
#define NC 256
#define HW 4096
#define AFWD 0.999f
#define EPS 1e-5f

#define NBLK 512
#define NTHR 512
#define PPB  16          // planes per block
#define LDSPL 4          // planes cached in LDS per block (waves 0..3)

typedef float f32x4 __attribute__((ext_vector_type(4)));

// Grid barrier: bar[0]=arrive count, bar[1]=generation. Device-scope atomics.
// Cooperative launch guarantees all NBLK blocks co-resident.
__device__ __forceinline__ void grid_barrier(unsigned* bar) {
    __syncthreads();
    if (threadIdx.x == 0) {
        __threadfence();
        unsigned g = __hip_atomic_load(&bar[1], __ATOMIC_RELAXED,
                                       __HIP_MEMORY_SCOPE_AGENT);
        unsigned a = __hip_atomic_fetch_add(&bar[0], 1u, __ATOMIC_SEQ_CST,
                                            __HIP_MEMORY_SCOPE_AGENT);
        if (a + 1u == (unsigned)NBLK) {
            __hip_atomic_store(&bar[0], 0u, __ATOMIC_RELAXED,
                               __HIP_MEMORY_SCOPE_AGENT);
            __hip_atomic_store(&bar[1], g + 1u, __ATOMIC_RELEASE,
                               __HIP_MEMORY_SCOPE_AGENT);
        } else {
            while (__hip_atomic_load(&bar[1], __ATOMIC_ACQUIRE,
                                     __HIP_MEMORY_SCOPE_AGENT) == g) {
                __builtin_amdgcn_s_sleep(8);
            }
        }
    }
    __syncthreads();
}

// ================= Fused cooperative kernel =================
__global__ __launch_bounds__(NTHR, 4) void cn_fused(
    const float* __restrict__ x,
    const float* __restrict__ m,
    const float* __restrict__ var,
    const float* __restrict__ m_p,
    const float* __restrict__ var_p,
    float* __restrict__ out,
    float* __restrict__ ws,
    unsigned* __restrict__ bar)
{
    __shared__ f32x4 ldsx[LDSPL * 1024];       // 64 KB: 4 planes
    __shared__ float e_seq[2 * NB - 1], e_seq2[2 * NB - 1];
    __shared__ float e_m[NB], e_v[NB], e_mu[NB], e_var[NB];
    __shared__ float e_munew[NB], e_varnew[NB];
    __shared__ float e_powv[NB];
    __shared__ float e_mB;

    float* mu_ws   = ws;               // [8192]
    float* v_ws    = ws + 8192;
    float* must_ws = ws + 2 * 8192;
    float* rs_ws   = ws + 3 * 8192;

    const int B = blockIdx.x;          // 0..511
    const int t = threadIdx.x;         // 0..511
    const int w = t >> 6;              // wave 0..7
    const int l = t & 63;

    const int pA = B * PPB + 2 * w;    // even plane: pinned registers
    const int pB = pA + 1;             // odd plane: LDS (w<4) or reread

    const f32x4* xA = (const f32x4*)(x + (size_t)pA * HW);
    const f32x4* xB = (const f32x4*)(x + (size_t)pB * HW);

    // ---------- Phase 1: load x once, accumulate stats ----------
    f32x4 rA[16];
    float sA = 0.f, ssA = 0.f, sB = 0.f, ssB = 0.f;

#pragma unroll
    for (int i = 0; i < 16; ++i) {
        f32x4 a = xA[i * 64 + l];
        rA[i] = a;
        sA  += a.x + a.y + a.z + a.w;
        ssA += a.x * a.x + a.y * a.y + a.z * a.z + a.w * a.w;
    }
    // Anti-remat pin: make each cached value an opaque asm-defined register so
    // the compiler cannot re-load it from x in phase 3 (round-3/4 failure mode).
#pragma unroll
    for (int i = 0; i < 16; ++i) {
        asm volatile("" : "+v"(rA[i].x), "+v"(rA[i].y), "+v"(rA[i].z), "+v"(rA[i].w));
    }

    if (w < LDSPL) {
#pragma unroll
        for (int i = 0; i < 16; ++i) {
            f32x4 b = xB[i * 64 + l];
            ldsx[w * 1024 + i * 64 + l] = b;
            sB  += b.x + b.y + b.z + b.w;
            ssB += b.x * b.x + b.y * b.y + b.z * b.z + b.w * b.w;
        }
    } else {
#pragma unroll
        for (int i = 0; i < 16; ++i) {
            f32x4 b = xB[i * 64 + l];
            sB  += b.x + b.y + b.z + b.w;
            ssB += b.x * b.x + b.y * b.y + b.z * b.z + b.w * b.w;
        }
    }

    // per-plane reduction fully inside the owning wave
#pragma unroll
    for (int off = 32; off > 0; off >>= 1) {
        sA  += __shfl_down(sA, off, 64);
        ssA += __shfl_down(ssA, off, 64);
        sB  += __shfl_down(sB, off, 64);
        ssB += __shfl_down(ssB, off, 64);
    }
    if (l == 0) {
        float mA = sA * (1.f / HW);
        mu_ws[pA] = mA;
        v_ws[pA]  = ssA * (1.f / HW) - mA * mA;
        float mBv = sB * (1.f / HW);
        mu_ws[pB] = mBv;
        v_ws[pB]  = ssB * (1.f / HW) - mBv * mBv;
    }

    grid_barrier(bar);

    // ---------- Phase 2: EMA chain; block B < NC handles channel c = B ----------
    const int c = B;
    if (c < NC) {
        if (t < NB - 1) {
            e_seq[t]  = m_p[(t + 1) * NC + c];
            e_seq2[t] = var_p[(t + 1) * NC + c];
        }
        if (t < NB) {
            float muv = mu_ws[t * NC + c];
            e_mu[t] = muv;
            e_seq[NB - 1 + t] = muv;
            e_m[t]   = m[t * NC + c];
            e_v[t]   = v_ws[t * NC + c];
            e_var[t] = var[t * NC + c];
        }
        if (t == 0) {
            float p = 1.f;
            for (int j = NB - 1; j >= 0; --j) { e_powv[j] = p; p *= AFWD; }
            e_mB = p;                          // AFWD^NB
        }
        __syncthreads();

        if (t < NB) {
            float tmp = 0.f;
#pragma unroll
            for (int j = 0; j < NB; ++j) tmp += e_powv[j] * e_seq[t + j];
            e_munew[t] = e_mB * e_m[t] + (1.f - AFWD) * tmp;
        }
        __syncthreads();

        if (t < NB) {
            float mst = t ? e_munew[t - 1] : e_m[NB - 1];
            float d = e_mu[t] - mst;
            e_seq2[NB - 1 + t] = e_v[t] + AFWD * d * d;
            must_ws[t * NC + c] = mst;
        }
        __syncthreads();

        if (t < NB) {
            float tmp = 0.f;
#pragma unroll
            for (int j = 0; j < NB; ++j) tmp += e_powv[j] * e_seq2[t + j];
            e_varnew[t] = e_mB * e_var[t] + (1.f - AFWD) * tmp;
        }
        __syncthreads();

        if (t < NB) {
            float vs = t ? e_varnew[t - 1] : e_var[NB - 1];
            rs_ws[t * NC + c] = 1.f / sqrtf(vs + EPS);
        }
    }

    grid_barrier(bar);

    // ---------- Phase 3: normalize from regs/LDS, NT store ----------
    const float muA = must_ws[pA], rsA = rs_ws[pA];
    const float muB = must_ws[pB], rsB = rs_ws[pB];
    f32x4* oA = (f32x4*)(out + (size_t)pA * HW);
    f32x4* oB = (f32x4*)(out + (size_t)pB * HW);

#pragma unroll
    for (int i = 0; i < 16; ++i) {
        f32x4 o = (rA[i] - muA) * rsA;
        __builtin_nontemporal_store(o, &oA[i * 64 + l]);
    }
    if (w < LDSPL) {
#pragma unroll
        for (int i = 0; i < 16; ++i) {
            f32x4 b = ldsx[w * 1024 + i * 64 + l];
            __builtin_nontemporal_store((b - muB) * rsB, &oB[i * 64 + l]);
        }
    } else {
#pragma unroll
        for (int i = 0; i < 16; ++i) {
            f32x4 b = xB[i * 64 + l];   // reread (L3-warm), 33 MB total
            __builtin_nontemporal_store((b - muB) * rsB, &oB[i * 64 + l]);
        }
    }
}

// ================= Fallback: 3-kernel path =================
__global__ __launch_bounds__(256) void cn_stats(const float* __restrict__ x,
                                                float* __restrict__ mu,
                                                float* __restrict__ v) {
    const int bc = blockIdx.x;
    const f32x4* xp = (const f32x4*)(x + (size_t)bc * HW);
    const int t = threadIdx.x;
    float s = 0.f, ss = 0.f;
#pragma unroll
    for (int i = 0; i < 4; ++i) {
        f32x4 val = xp[t + i * 256];
        s  += val.x + val.y + val.z + val.w;
        ss += val.x * val.x + val.y * val.y + val.z * val.z + val.w * val.w;
    }
#pragma unroll
    for (int off = 32; off > 0; off >>= 1) {
        s  += __shfl_down(s, off, 64);
        ss += __shfl_down(ss, off, 64);
    }
    __shared__ float sbuf[4], ssbuf[4];
    const int wave = t >> 6, lane = t & 63;
    if (lane == 0) { sbuf[wave] = s; ssbuf[wave] = ss; }
    __syncthreads();
    if (t == 0) {
        float S  = sbuf[0] + sbuf[1] + sbuf[2] + sbuf[3];
        float SS = ssbuf[0] + ssbuf[1] + ssbuf[2] + ssbuf[3];
        float mean = S * (1.f / HW);
        mu[bc] = mean;
        v[bc]  = SS * (1.f / HW) - mean * mean;
    }
}

__global__ __launch_bounds__(64) void cn_ema(const float* __restrict__ mu,
                                             const float* __restrict__ v,
                                             const float* __restrict__ m,
                                             const float* __restrict__ var,
                                             const float* __restrict__ m_p,
                                             const float* __restrict__ var_p,
                                             float* __restrict__ mu_stale,
                                             float* __restrict__ rscale) {
    const int c = blockIdx.x;
    const int t = threadIdx.x;
    __shared__ float seq[2 * NB - 1], seq2[2 * NB - 1];
    __shared__ float m_s[NB], v_s[NB], mu_s[NB], var_s[NB];
    __shared__ float mu_new[NB], var_new[NB];
    if (t < NB - 1) { seq[t] = m_p[(t + 1) * NC + c]; seq2[t] = var_p[(t + 1) * NC + c]; }
    if (t < NB) {
        float muv = mu[t * NC + c];
        mu_s[t] = muv; seq[NB - 1 + t] = muv;
        m_s[t] = m[t * NC + c]; v_s[t] = v[t * NC + c]; var_s[t] = var[t * NC + c];
    }
    float powv[NB];
    float p = 1.f;
#pragma unroll
    for (int j = NB - 1; j >= 0; --j) { powv[j] = p; p *= AFWD; }
    const float mB = p;
    __syncthreads();
    if (t < NB) {
        float tmp = 0.f;
#pragma unroll
        for (int j = 0; j < NB; ++j) tmp += powv[j] * seq[t + j];
        mu_new[t] = mB * m_s[t] + (1.f - AFWD) * tmp;
    }
    __syncthreads();
    if (t < NB) {
        float mst = t ? mu_new[t - 1] : m_s[NB - 1];
        float d = mu_s[t] - mst;
        seq2[NB - 1 + t] = v_s[t] + AFWD * d * d;
        mu_stale[t * NC + c] = mst;
    }
    __syncthreads();
    if (t < NB) {
        float tmp = 0.f;
#pragma unroll
        for (int j = 0; j < NB; ++j) tmp += powv[j] * seq2[t + j];
        var_new[t] = mB * var_s[t] + (1.f - AFWD) * tmp;
    }
    __syncthreads();
    if (t < NB) {
        float vs = t ? var_new[t - 1] : var_s[NB - 1];
        rscale[t * NC + c] = 1.f / sqrtf(vs + EPS);
    }
}

__global__ __launch_bounds__(256) void cn_norm(const float* __restrict__ x,
                                               const float* __restrict__ mu_stale,
                                               const float* __restrict__ rscale,
                                               float* __restrict__ out) {
    const int bc = blockIdx.x;
    const float mean = mu_stale[bc];
    const float rs   = rscale[bc];
    const f32x4* xp = (const f32x4*)(x + (size_t)bc * HW);
    f32x4* op       = (f32x4*)(out + (size_t)bc * HW);
    const int t = threadIdx.x;
#pragma unroll
    for (int i = 0; i < 4; ++i) {
        f32x4 val = xp[t + i * 256];
        __builtin_nontemporal_store((val - mean) * rs, &op[t + i * 256]);
    }
}

extern "C" void kernel_launch(void* const* d_in, const int* in_sizes, int n_in,
                              void* d_out, int out_size, void* d_ws, size_t ws_size,
                              hipStream_t stream) {
    const float* x     = (const float*)d_in[0];
    const float* m     = (const float*)d_in[1];
    const float* var   = (const float*)d_in[2];
    const float* m_p   = (const float*)d_in[3];
    const float* var_p = (const float*)d_in[4];
    float* out = (float*)d_out;
    float* ws  = (float*)d_ws;
    unsigned* bar = (unsigned*)(ws + 4 * 8192);

    hipMemsetAsync(bar, 0, 2 * sizeof(unsigned), stream);

    void* args[] = { (void*)&x, (void*)&m, (void*)&var, (void*)&m_p,
                     (void*)&var_p, (void*)&out, (void*)&ws, (void*)&bar };
    hipError_t err = hipLaunchCooperativeKernel(
        (const void*)cn_fused, dim3(NBLK), dim3(NTHR), args, 0, stream);

    if (err != hipSuccess) {
        float* mu       = ws;
        float* v        = ws + NB * NC;
        float* mu_stale = ws + 2 * NB * NC;
        float* rscale   = ws + 3 * NB * NC;
        cn_stats<<<NB * NC, 256, 0, stream>>>(x, mu, v);
        cn_ema<<<NC, 64, 0, stream>>>(mu, v, m, var, m_p, var_p, mu_stale, rscale);
        cn_norm<<<NB * NC, 256, 0, stream>>>(x, mu_stale, rscale, out);
    }
}

// Round 6
// 168.806 us; speedup vs baseline: 1.8180x; 1.8180x over previous
//
#include <hip/hip_runtime.h>

#define NB 32
#define NC 256
#define HW 4096
#define AFWD 0.999f
#define EPS 1e-5f

#define NBLK 256
#define NTHR 1024
#define PPB  32          // planes per block
#define LDSPL 9          // planes cached in dynamic LDS (waves 0..8), 144 KB

typedef float f32x4 __attribute__((ext_vector_type(4)));

// Grid barrier: bar[0]=arrive count, bar[1]=generation. Device-scope atomics.
// Cooperative launch guarantees all NBLK blocks co-resident.
__device__ __forceinline__ void grid_barrier(unsigned* bar) {
    __syncthreads();
    if (threadIdx.x == 0) {
        __threadfence();
        unsigned g = __hip_atomic_load(&bar[1], __ATOMIC_RELAXED,
                                       __HIP_MEMORY_SCOPE_AGENT);
        unsigned a = __hip_atomic_fetch_add(&bar[0], 1u, __ATOMIC_SEQ_CST,
                                            __HIP_MEMORY_SCOPE_AGENT);
        if (a + 1u == (unsigned)NBLK) {
            __hip_atomic_store(&bar[0], 0u, __ATOMIC_RELAXED,
                               __HIP_MEMORY_SCOPE_AGENT);
            __hip_atomic_store(&bar[1], g + 1u, __ATOMIC_RELEASE,
                               __HIP_MEMORY_SCOPE_AGENT);
        } else {
            while (__hip_atomic_load(&bar[1], __ATOMIC_ACQUIRE,
                                     __HIP_MEMORY_SCOPE_AGENT) == g) {
                __builtin_amdgcn_s_sleep(8);
            }
        }
    }
    __syncthreads();
}

// ================= Fused cooperative kernel =================
// waves_per_eu(4,4): pin BOTH min and max occupancy -> VGPR budget 128.
// (launch_bounds' 2nd arg sets only the MIN -> compiler targeted 8 waves/EU
//  = 64 VGPR and spilled the register cache in rounds 3-5.)
__global__ __attribute__((amdgpu_flat_work_group_size(NTHR, NTHR),
                          amdgpu_waves_per_eu(4, 4)))
void cn_fused(
    const float* __restrict__ x,
    const float* __restrict__ m,
    const float* __restrict__ var,
    const float* __restrict__ m_p,
    const float* __restrict__ var_p,
    float* __restrict__ out,
    float* __restrict__ ws,
    unsigned* __restrict__ bar)
{
    extern __shared__ f32x4 ldsx[];            // [LDSPL * 1024] = 144 KB
    __shared__ float e_seq[2 * NB - 1], e_seq2[2 * NB - 1];
    __shared__ float e_m[NB], e_v[NB], e_mu[NB], e_var[NB];
    __shared__ float e_munew[NB], e_varnew[NB];
    __shared__ float e_powv[NB];
    __shared__ float e_mB;

    float* mu_ws   = ws;               // [8192]
    float* v_ws    = ws + 8192;
    float* must_ws = ws + 2 * 8192;
    float* rs_ws   = ws + 3 * 8192;

    const int B = blockIdx.x;          // 0..255 (== channel for EMA phase)
    const int t = threadIdx.x;         // 0..1023
    const int w = t >> 6;              // wave 0..15
    const int l = t & 63;

    const int pA = B * PPB + 2 * w;    // even plane: pinned registers
    const int pB = pA + 1;             // odd plane: LDS (w<LDSPL) or reread

    const f32x4* xA = (const f32x4*)(x + (size_t)pA * HW);
    const f32x4* xB = (const f32x4*)(x + (size_t)pB * HW);

    // ---------- Phase 1: load x once, accumulate stats ----------
    f32x4 rA[16];
    float sA = 0.f, ssA = 0.f, sB = 0.f, ssB = 0.f;

#pragma unroll
    for (int i = 0; i < 16; ++i) {
        f32x4 a = xA[i * 64 + l];
        rA[i] = a;
        sA  += a.x + a.y + a.z + a.w;
        ssA += a.x * a.x + a.y * a.y + a.z * a.z + a.w * a.w;
    }
    // Anti-remat pin: compiler may not re-derive these from x in phase 3.
#pragma unroll
    for (int i = 0; i < 16; ++i) {
        asm volatile("" : "+v"(rA[i].x), "+v"(rA[i].y), "+v"(rA[i].z), "+v"(rA[i].w));
    }

    if (w < LDSPL) {
#pragma unroll
        for (int i = 0; i < 16; ++i) {
            f32x4 b = xB[i * 64 + l];
            ldsx[w * 1024 + i * 64 + l] = b;
            sB  += b.x + b.y + b.z + b.w;
            ssB += b.x * b.x + b.y * b.y + b.z * b.z + b.w * b.w;
        }
    } else {
#pragma unroll
        for (int i = 0; i < 16; ++i) {
            f32x4 b = xB[i * 64 + l];
            sB  += b.x + b.y + b.z + b.w;
            ssB += b.x * b.x + b.y * b.y + b.z * b.z + b.w * b.w;
        }
    }

    // per-plane reduction fully inside the owning wave
#pragma unroll
    for (int off = 32; off > 0; off >>= 1) {
        sA  += __shfl_down(sA, off, 64);
        ssA += __shfl_down(ssA, off, 64);
        sB  += __shfl_down(sB, off, 64);
        ssB += __shfl_down(ssB, off, 64);
    }
    if (l == 0) {
        float mA = sA * (1.f / HW);
        mu_ws[pA] = mA;
        v_ws[pA]  = ssA * (1.f / HW) - mA * mA;
        float mBv = sB * (1.f / HW);
        mu_ws[pB] = mBv;
        v_ws[pB]  = ssB * (1.f / HW) - mBv * mBv;
    }

    grid_barrier(bar);

    // ---------- Phase 2: EMA chain; block B handles channel c = B ----------
    const int c = B;
    if (t < NB - 1) {
        e_seq[t]  = m_p[(t + 1) * NC + c];
        e_seq2[t] = var_p[(t + 1) * NC + c];
    }
    if (t < NB) {
        float muv = mu_ws[t * NC + c];
        e_mu[t] = muv;
        e_seq[NB - 1 + t] = muv;
        e_m[t]   = m[t * NC + c];
        e_v[t]   = v_ws[t * NC + c];
        e_var[t] = var[t * NC + c];
    }
    if (t == 0) {
        float p = 1.f;
        for (int j = NB - 1; j >= 0; --j) { e_powv[j] = p; p *= AFWD; }
        e_mB = p;                          // AFWD^NB
    }
    __syncthreads();

    if (t < NB) {
        float tmp = 0.f;
#pragma unroll
        for (int j = 0; j < NB; ++j) tmp += e_powv[j] * e_seq[t + j];
        e_munew[t] = e_mB * e_m[t] + (1.f - AFWD) * tmp;
    }
    __syncthreads();

    if (t < NB) {
        float mst = t ? e_munew[t - 1] : e_m[NB - 1];
        float d = e_mu[t] - mst;
        e_seq2[NB - 1 + t] = e_v[t] + AFWD * d * d;
        must_ws[t * NC + c] = mst;
    }
    __syncthreads();

    if (t < NB) {
        float tmp = 0.f;
#pragma unroll
        for (int j = 0; j < NB; ++j) tmp += e_powv[j] * e_seq2[t + j];
        e_varnew[t] = e_mB * e_var[t] + (1.f - AFWD) * tmp;
    }
    __syncthreads();

    if (t < NB) {
        float vs = t ? e_varnew[t - 1] : e_var[NB - 1];
        rs_ws[t * NC + c] = 1.f / sqrtf(vs + EPS);
    }

    grid_barrier(bar);

    // ---------- Phase 3: normalize from regs/LDS, NT store ----------
    const float muA = must_ws[pA], rsA = rs_ws[pA];
    const float muB = must_ws[pB], rsB = rs_ws[pB];
    f32x4* oA = (f32x4*)(out + (size_t)pA * HW);
    f32x4* oB = (f32x4*)(out + (size_t)pB * HW);

#pragma unroll
    for (int i = 0; i < 16; ++i) {
        f32x4 o = (rA[i] - muA) * rsA;
        __builtin_nontemporal_store(o, &oA[i * 64 + l]);
    }
    if (w < LDSPL) {
#pragma unroll
        for (int i = 0; i < 16; ++i) {
            f32x4 b = ldsx[w * 1024 + i * 64 + l];
            __builtin_nontemporal_store((b - muB) * rsB, &oB[i * 64 + l]);
        }
    } else {
#pragma unroll
        for (int i = 0; i < 16; ++i) {
            f32x4 b = xB[i * 64 + l];   // reread (29 MB total, L3-warm)
            __builtin_nontemporal_store((b - muB) * rsB, &oB[i * 64 + l]);
        }
    }
}

// ================= Fallback: 3-kernel path =================
__global__ __launch_bounds__(256) void cn_stats(const float* __restrict__ x,
                                                float* __restrict__ mu,
                                                float* __restrict__ v) {
    const int bc = blockIdx.x;
    const f32x4* xp = (const f32x4*)(x + (size_t)bc * HW);
    const int t = threadIdx.x;
    float s = 0.f, ss = 0.f;
#pragma unroll
    for (int i = 0; i < 4; ++i) {
        f32x4 val = xp[t + i * 256];
        s  += val.x + val.y + val.z + val.w;
        ss += val.x * val.x + val.y * val.y + val.z * val.z + val.w * val.w;
    }
#pragma unroll
    for (int off = 32; off > 0; off >>= 1) {
        s  += __shfl_down(s, off, 64);
        ss += __shfl_down(ss, off, 64);
    }
    __shared__ float sbuf[4], ssbuf[4];
    const int wave = t >> 6, lane = t & 63;
    if (lane == 0) { sbuf[wave] = s; ssbuf[wave] = ss; }
    __syncthreads();
    if (t == 0) {
        float S  = sbuf[0] + sbuf[1] + sbuf[2] + sbuf[3];
        float SS = ssbuf[0] + ssbuf[1] + ssbuf[2] + ssbuf[3];
        float mean = S * (1.f / HW);
        mu[bc] = mean;
        v[bc]  = SS * (1.f / HW) - mean * mean;
    }
}

__global__ __launch_bounds__(64) void cn_ema(const float* __restrict__ mu,
                                             const float* __restrict__ v,
                                             const float* __restrict__ m,
                                             const float* __restrict__ var,
                                             const float* __restrict__ m_p,
                                             const float* __restrict__ var_p,
                                             float* __restrict__ mu_stale,
                                             float* __restrict__ rscale) {
    const int c = blockIdx.x;
    const int t = threadIdx.x;
    __shared__ float seq[2 * NB - 1], seq2[2 * NB - 1];
    __shared__ float m_s[NB], v_s[NB], mu_s[NB], var_s[NB];
    __shared__ float mu_new[NB], var_new[NB];
    if (t < NB - 1) { seq[t] = m_p[(t + 1) * NC + c]; seq2[t] = var_p[(t + 1) * NC + c]; }
    if (t < NB) {
        float muv = mu[t * NC + c];
        mu_s[t] = muv; seq[NB - 1 + t] = muv;
        m_s[t] = m[t * NC + c]; v_s[t] = v[t * NC + c]; var_s[t] = var[t * NC + c];
    }
    float powv[NB];
    float p = 1.f;
#pragma unroll
    for (int j = NB - 1; j >= 0; --j) { powv[j] = p; p *= AFWD; }
    const float mB = p;
    __syncthreads();
    if (t < NB) {
        float tmp = 0.f;
#pragma unroll
        for (int j = 0; j < NB; ++j) tmp += powv[j] * seq[t + j];
        mu_new[t] = mB * m_s[t] + (1.f - AFWD) * tmp;
    }
    __syncthreads();
    if (t < NB) {
        float mst = t ? mu_new[t - 1] : m_s[NB - 1];
        float d = mu_s[t] - mst;
        seq2[NB - 1 + t] = v_s[t] + AFWD * d * d;
        mu_stale[t * NC + c] = mst;
    }
    __syncthreads();
    if (t < NB) {
        float tmp = 0.f;
#pragma unroll
        for (int j = 0; j < NB; ++j) tmp += powv[j] * seq2[t + j];
        var_new[t] = mB * var_s[t] + (1.f - AFWD) * tmp;
    }
    __syncthreads();
    if (t < NB) {
        float vs = t ? var_new[t - 1] : var_s[NB - 1];
        rscale[t * NC + c] = 1.f / sqrtf(vs + EPS);
    }
}

__global__ __launch_bounds__(256) void cn_norm(const float* __restrict__ x,
                                               const float* __restrict__ mu_stale,
                                               const float* __restrict__ rscale,
                                               float* __restrict__ out) {
    const int bc = blockIdx.x;
    const float mean = mu_stale[bc];
    const float rs   = rscale[bc];
    const f32x4* xp = (const f32x4*)(x + (size_t)bc * HW);
    f32x4* op       = (f32x4*)(out + (size_t)bc * HW);
    const int t = threadIdx.x;
#pragma unroll
    for (int i = 0; i < 4; ++i) {
        f32x4 val = xp[t + i * 256];
        __builtin_nontemporal_store((val - mean) * rs, &op[t + i * 256]);
    }
}

extern "C" void kernel_launch(void* const* d_in, const int* in_sizes, int n_in,
                              void* d_out, int out_size, void* d_ws, size_t ws_size,
                              hipStream_t stream) {
    const float* x     = (const float*)d_in[0];
    const float* m     = (const float*)d_in[1];
    const float* var   = (const float*)d_in[2];
    const float* m_p   = (const float*)d_in[3];
    const float* var_p = (const float*)d_in[4];
    float* out = (float*)d_out;
    float* ws  = (float*)d_ws;
    unsigned* bar = (unsigned*)(ws + 4 * 8192);

    hipMemsetAsync(bar, 0, 2 * sizeof(unsigned), stream);

    void* args[] = { (void*)&x, (void*)&m, (void*)&var, (void*)&m_p,
                     (void*)&var_p, (void*)&out, (void*)&ws, (void*)&bar };
    hipError_t err = hipLaunchCooperativeKernel(
        (const void*)cn_fused, dim3(NBLK), dim3(NTHR), args,
        LDSPL * 1024 * sizeof(f32x4), stream);

    if (err != hipSuccess) {
        float* mu       = ws;
        float* v        = ws + NB * NC;
        float* mu_stale = ws + 2 * NB * NC;
        float* rscale   = ws + 3 * NB * NC;
        cn_stats<<<NB * NC, 256, 0, stream>>>(x, mu, v);
        cn_ema<<<NC, 64, 0, stream>>>(mu, v, m, var, m_p, var_p, mu_stale, rscale);
        cn_norm<<<NB * NC, 256, 0, stream>>>(x, mu_stale, rscale, out);
    }
}

// Round 7
// 63.950 us; speedup vs baseline: 4.7989x; 2.6396x over previous
//
#include <hip/hip_runtime.h>

#define NB 32
#define NC 256
#define HW 4096
#define AFWD 0.999f
#define EPS 1e-5f

typedef float f32x4 __attribute__((ext_vector_type(4)));

// One block per channel. Block = 1024 threads = 16 waves; wave w owns batch
// planes 2w and 2w+1 of this channel. The EMA chain couples only across the
// batch dim WITHIN a channel, so everything stays block-local: no grid sync.
__global__ __launch_bounds__(1024) void cn_channel(
    const float* __restrict__ x,
    const float* __restrict__ m,
    const float* __restrict__ var,
    const float* __restrict__ m_p,
    const float* __restrict__ var_p,
    float* __restrict__ out)
{
    const int c = blockIdx.x;          // channel 0..255
    const int t = threadIdx.x;         // 0..1023
    const int w = t >> 6;              // wave 0..15
    const int l = t & 63;

    __shared__ float s_mu[NB], s_v[NB];          // per-batch stats
    __shared__ float s_must[NB], s_rs[NB];       // stale mean, 1/scale
    __shared__ float e_seq[2 * NB - 1], e_seq2[2 * NB - 1];
    __shared__ float e_m[NB], e_var[NB];
    __shared__ float e_munew[NB], e_varnew[NB];
    __shared__ float e_powv[NB];
    __shared__ float e_mB;

    const int bA = 2 * w, bB = 2 * w + 1;        // batch indices of this wave
    const f32x4* xA = (const f32x4*)(x + ((size_t)bA * NC + c) * HW);
    const f32x4* xB = (const f32x4*)(x + ((size_t)bB * NC + c) * HW);

    // ---------- Pass 1: streaming stats (no caching) ----------
    float sA = 0.f, ssA = 0.f, sB = 0.f, ssB = 0.f;
#pragma unroll
    for (int i = 0; i < 16; ++i) {
        f32x4 a = xA[i * 64 + l];
        sA  += a.x + a.y + a.z + a.w;
        ssA += a.x * a.x + a.y * a.y + a.z * a.z + a.w * a.w;
        f32x4 b = xB[i * 64 + l];
        sB  += b.x + b.y + b.z + b.w;
        ssB += b.x * b.x + b.y * b.y + b.z * b.z + b.w * b.w;
    }
#pragma unroll
    for (int off = 32; off > 0; off >>= 1) {
        sA  += __shfl_down(sA, off, 64);
        ssA += __shfl_down(ssA, off, 64);
        sB  += __shfl_down(sB, off, 64);
        ssB += __shfl_down(ssB, off, 64);
    }
    if (l == 0) {
        float mA = sA * (1.f / HW);
        s_mu[bA] = mA;
        s_v[bA]  = ssA * (1.f / HW) - mA * mA;
        float mBv = sB * (1.f / HW);
        s_mu[bB] = mBv;
        s_v[bB]  = ssB * (1.f / HW) - mBv * mBv;
    }
    __syncthreads();

    // ---------- In-block EMA chain (threads 0..NB-1) ----------
    if (t < NB - 1) {
        e_seq[t]  = m_p[(t + 1) * NC + c];
        e_seq2[t] = var_p[(t + 1) * NC + c];
    }
    if (t < NB) {
        e_seq[NB - 1 + t] = s_mu[t];
        e_m[t]   = m[t * NC + c];
        e_var[t] = var[t * NC + c];
    }
    if (t == 0) {
        float p = 1.f;
        for (int j = NB - 1; j >= 0; --j) { e_powv[j] = p; p *= AFWD; }
        e_mB = p;                              // AFWD^NB
    }
    __syncthreads();

    if (t < NB) {
        float tmp = 0.f;
#pragma unroll
        for (int j = 0; j < NB; ++j) tmp += e_powv[j] * e_seq[t + j];
        e_munew[t] = e_mB * e_m[t] + (1.f - AFWD) * tmp;
    }
    __syncthreads();

    if (t < NB) {
        float mst = t ? e_munew[t - 1] : e_m[NB - 1];
        s_must[t] = mst;
        float d = s_mu[t] - mst;
        e_seq2[NB - 1 + t] = s_v[t] + AFWD * d * d;
    }
    __syncthreads();

    if (t < NB) {
        float tmp = 0.f;
#pragma unroll
        for (int j = 0; j < NB; ++j) tmp += e_powv[j] * e_seq2[t + j];
        e_varnew[t] = e_mB * e_var[t] + (1.f - AFWD) * tmp;
    }
    __syncthreads();

    if (t < NB) {
        float vs = t ? e_varnew[t - 1] : e_var[NB - 1];
        s_rs[t] = 1.f / sqrtf(vs + EPS);
    }
    __syncthreads();

    // ---------- Pass 2: reread (L3-warm), normalize, NT store ----------
    const float muA = s_must[bA], rsA = s_rs[bA];
    const float muB = s_must[bB], rsB = s_rs[bB];
    f32x4* oA = (f32x4*)(out + ((size_t)bA * NC + c) * HW);
    f32x4* oB = (f32x4*)(out + ((size_t)bB * NC + c) * HW);

#pragma unroll
    for (int i = 0; i < 16; ++i) {
        f32x4 a = xA[i * 64 + l];
        __builtin_nontemporal_store((a - muA) * rsA, &oA[i * 64 + l]);
        f32x4 b = xB[i * 64 + l];
        __builtin_nontemporal_store((b - muB) * rsB, &oB[i * 64 + l]);
    }
}

extern "C" void kernel_launch(void* const* d_in, const int* in_sizes, int n_in,
                              void* d_out, int out_size, void* d_ws, size_t ws_size,
                              hipStream_t stream) {
    const float* x     = (const float*)d_in[0];
    const float* m     = (const float*)d_in[1];
    const float* var   = (const float*)d_in[2];
    const float* m_p   = (const float*)d_in[3];
    const float* var_p = (const float*)d_in[4];
    float* out = (float*)d_out;

    cn_channel<<<NC, 1024, 0, stream>>>(x, m, var, m_p, var_p, out);
}